// Round 13
// baseline (555.628 us; speedup 1.0000x reference)
//
#include <hip/hip_runtime.h>

#define N_  30000
#define E_  480000

typedef short short8 __attribute__((ext_vector_type(8)));
typedef float f32x4  __attribute__((ext_vector_type(4)));
typedef unsigned int u32x4 __attribute__((ext_vector_type(4)));
union Frag { u32x4 q; short8 v; unsigned short us[8]; };

__device__ __forceinline__ float b2f(unsigned short u){
  union { unsigned int i; float f; } v; v.i = ((unsigned int)u) << 16; return v.f;
}
__device__ __forceinline__ unsigned short f2b(float f){
  union { float f; unsigned int u; } v; v.f = f;
  unsigned int u = v.u;
  return (unsigned short)((u + 0x7fffu + ((u >> 16) & 1u)) >> 16);
}

// ---- init scratch + convert weights AND feat to bf16 ----
__global__ void k_initconv(const float* __restrict__ Wfc, const float* __restrict__ Wres,
                           const float* __restrict__ Wout, const float* __restrict__ feat,
                           unsigned short* __restrict__ Wt, unsigned short* __restrict__ WtOut,
                           unsigned short* __restrict__ featb,
                           int* __restrict__ counts, int* __restrict__ cursor){
  int gid = blockIdx.x * 256 + threadIdx.x;
  int stride = gridDim.x * 256;
  if (gid < N_){ counts[gid] = 0; cursor[gid] = 0; }
  const int total1 = 1024 * 128;
  const int total2 = 128 * 512;
  for (int i = gid; i < total1 + total2; i += stride){
    if (i < total1){
      int c = i >> 7, k = i & 127;
      float v = (c < 512) ? Wfc[k * 512 + c] : Wres[k * 512 + (c - 512)];
      Wt[c * 128 + k] = f2b(v);
    } else {
      int j = i - total1;
      int n = j >> 9, k = j & 511;
      WtOut[n * 512 + k] = f2b(Wout[k * 128 + n]);
    }
  }
  for (int i = gid; i < N_ * 128; i += stride)
    featb[i] = f2b(feat[i]);
}

// ---- histogram of dst ----
__global__ void k_hist(const int* __restrict__ dst, int* __restrict__ counts){
  int e = blockIdx.x * 256 + threadIdx.x;
  if (e < E_) atomicAdd(&counts[dst[e]], 1);
}

// ---- exclusive scan -> offs[0..N_]: 1 block, register-serial + shuffle ----
__global__ __launch_bounds__(1024) void k_scan(const int* __restrict__ counts,
                                               int* __restrict__ offs){
  __shared__ int wsum[16];
  int t = threadIdx.x;
  int lane = t & 63, w = t >> 6;
  int base = t * 32;
  int vals[32];
  int s = 0;
#pragma unroll
  for (int j = 0; j < 32; j++){
    int idx = base + j;
    int v = (idx < N_) ? counts[idx] : 0;
    vals[j] = s;
    s += v;
  }
  int x = s;
  for (int o = 1; o < 64; o <<= 1){
    int y = __shfl_up(x, o);
    if (lane >= o) x += y;
  }
  if (lane == 63) wsum[w] = x;
  __syncthreads();
  if (t < 16){
    int y = wsum[t];
    for (int o = 1; o < 16; o <<= 1){
      int z = __shfl_up(y, o, 16);
      if (t >= o) y += z;
    }
    wsum[t] = y;
  }
  __syncthreads();
  int wbase = (w > 0) ? wsum[w - 1] : 0;
  int ex = wbase + x - s;
#pragma unroll
  for (int j = 0; j < 32; j++){
    int idx = base + j;
    if (idx <= N_) offs[idx] = ex + vals[j];
  }
}

// ---- GEMM1 (MFMA): bf16 feat, 64 rows x 256 cols/block, fused el/er ----
__global__ __launch_bounds__(256) void k_gemm1(const unsigned short* __restrict__ featb,
                                               const unsigned short* __restrict__ Wt,
                                               const float* __restrict__ al,
                                               const float* __restrict__ ar,
                                               unsigned short* __restrict__ comb,
                                               float* __restrict__ el,
                                               float* __restrict__ er){
  int tid = threadIdx.x;
  int wave = tid >> 6, lane = tid & 63;
  int lrow = lane & 15, quad = lane >> 4;
  int rowbase = blockIdx.x * 64 + wave * 16;
  int colbase = blockIdx.y * 256;
  int arow = rowbase + lrow; if (arow > N_ - 1) arow = N_ - 1;
  const unsigned short* aptr = featb + arow * 128 + quad * 8;
  f32x4 acc[16] = {};
#pragma unroll
  for (int kk = 0; kk < 4; kk++){
    Frag a; a.q = *reinterpret_cast<const u32x4*>(aptr + kk * 32);
#pragma unroll
    for (int s = 0; s < 16; s++){
      int col = colbase + s * 16 + lrow;
      Frag b; b.q = *reinterpret_cast<const u32x4*>(Wt + col * 128 + kk * 32 + quad * 8);
      acc[s] = __builtin_amdgcn_mfma_f32_16x16x32_bf16(a.v, b.v, acc[s], 0, 0, 0);
    }
  }
#pragma unroll
  for (int s = 0; s < 16; s++){
    int col = colbase + s * 16 + lrow;
#pragma unroll
    for (int j = 0; j < 4; j++){
      int gr = rowbase + quad * 4 + j;
      if (gr < N_) comb[gr * 1024 + col] = f2b(acc[s][j]);
    }
  }
  if (blockIdx.y < 2){
    int h0 = blockIdx.y * 2;
    float pl[2][4] = {}, pr[2][4] = {};
#pragma unroll
    for (int s = 0; s < 16; s++){
      int hh = s >> 3;
      int d = (s & 7) * 16 + lrow;
      float av = al[(h0 + hh) * 128 + d];
      float rv = ar[(h0 + hh) * 128 + d];
#pragma unroll
      for (int j = 0; j < 4; j++){
        pl[hh][j] += acc[s][j] * av;
        pr[hh][j] += acc[s][j] * rv;
      }
    }
    for (int o = 8; o >= 1; o >>= 1){
#pragma unroll
      for (int hh = 0; hh < 2; hh++)
#pragma unroll
        for (int j = 0; j < 4; j++){
          pl[hh][j] += __shfl_down(pl[hh][j], o, 16);
          pr[hh][j] += __shfl_down(pr[hh][j], o, 16);
        }
    }
    if (lrow == 0){
#pragma unroll
      for (int j = 0; j < 4; j++){
        int gr = rowbase + quad * 4 + j;
        if (gr < N_){
#pragma unroll
          for (int hh = 0; hh < 2; hh++){
            el[gr * 4 + h0 + hh] = pl[hh][j];
            er[gr * 4 + h0 + hh] = pr[hh][j];
          }
        }
      }
    }
  }
}

// ---- per-edge score (leaky relu) + CSR scatter ----
__global__ void k_edge(const int* __restrict__ src, const int* __restrict__ dst,
                       const float* __restrict__ el, const float* __restrict__ er,
                       float* __restrict__ escore, const int* __restrict__ offs,
                       int* __restrict__ cursor, int* __restrict__ eid){
  int e = blockIdx.x * 256 + threadIdx.x;
  if (e >= E_) return;
  int s = src[e], d = dst[e];
  f32x4 a = *reinterpret_cast<const f32x4*>(el + s * 4);
  f32x4 b = *reinterpret_cast<const f32x4*>(er + d * 4);
  f32x4 v = a + b;
#pragma unroll
  for (int i = 0; i < 4; i++) v[i] = v[i] > 0.f ? v[i] : 0.2f * v[i];
  *reinterpret_cast<f32x4*>(escore + e * 4) = v;
  int p = atomicAdd(&cursor[d], 1);
  eid[offs[d] + p] = e;
}

// ---- softmax hoist: normalize escore IN PLACE to attention weights ----
// one wave per node; 16-lane group per head.
__global__ __launch_bounds__(256) void k_soft(const int* __restrict__ offs,
                                              const int* __restrict__ eid,
                                              float* __restrict__ escore){
  int wave = threadIdx.x >> 6, lane = threadIdx.x & 63;
  int n = blockIdx.x * 4 + wave;
  if (n >= N_) return;
  int head = lane >> 4, sub = lane & 15;
  int off0 = offs[n], g = offs[n + 1] - off0;
  float m = -1e30f;
  for (int i = sub; i < g; i += 16)
    m = fmaxf(m, escore[eid[off0 + i] * 4 + head]);
  for (int o = 8; o >= 1; o >>= 1) m = fmaxf(m, __shfl_xor(m, o, 16));
  float ss = 0.f;
  for (int i = sub; i < g; i += 16)
    ss += __expf(escore[eid[off0 + i] * 4 + head] - m);
  for (int o = 8; o >= 1; o >>= 1) ss += __shfl_xor(ss, o, 16);
  float rd = (ss > 0.f) ? 1.0f / ss : 0.f;
  for (int i = sub; i < g; i += 16){
    int idx = eid[off0 + i] * 4 + head;
    escore[idx] = __expf(escore[idx] - m) * rd;
  }
}

// ---- gather: CHANNEL-SLICED for L2 locality. blockIdx.x & 7 = 64-ch slice
// (XCD-affine under round-robin dispatch: per-XCD working set 30000*128B = 3.84MB
//  fits the 4MB per-XCD L2). 4 waves/block = 4 nodes; lane owns 1 channel.
__global__ __launch_bounds__(256) void k_aggr(const int* __restrict__ offs,
                                              const int* __restrict__ eid,
                                              const int* __restrict__ src,
                                              const float* __restrict__ w,
                                              unsigned short* __restrict__ comb,
                                              const float* __restrict__ bias){
  int wave = threadIdx.x >> 6, lane = threadIdx.x & 63;
  int cb = blockIdx.x & 7;
  int n = (blockIdx.x >> 3) * 4 + wave;
  if (n >= N_) return;
  int c = cb * 64 + lane;          // channel 0..511
  int head = c >> 7;               // uniform per block
  int off0 = offs[n], g = offs[n + 1] - off0;

  float acc = 0.f;
  int i = 0;
  for (; i + 7 < g; i += 8){
    int e8[8], s8[8];
    float w8[8];
    unsigned short d8[8];
#pragma unroll
    for (int u = 0; u < 8; u++) e8[u] = eid[off0 + i + u];
#pragma unroll
    for (int u = 0; u < 8; u++) s8[u] = src[e8[u]];
#pragma unroll
    for (int u = 0; u < 8; u++) w8[u] = w[e8[u] * 4 + head];
#pragma unroll
    for (int u = 0; u < 8; u++) d8[u] = comb[s8[u] * 1024 + c];
#pragma unroll
    for (int u = 0; u < 8; u++) acc += w8[u] * b2f(d8[u]);
  }
  for (; i < g; i++){
    int e = eid[off0 + i];
    acc += w[e * 4 + head] * b2f(comb[src[e] * 1024 + c]);
  }

  unsigned short* rp = comb + n * 1024 + 512 + c;
  float r = acc + b2f(*rp) + bias[c];
  *rp = f2b(r);
}

// ---- BN stats: 256 blocks, wave-register partials + LDS block-reduce ----
__global__ __launch_bounds__(256) void k_stats(const unsigned short* __restrict__ comb,
                                               float* __restrict__ psum,
                                               float* __restrict__ psq){
  __shared__ float lsum[4][512];
  __shared__ float lsq[4][512];
  int t = threadIdx.x, lane = t & 63, rg = t >> 6;
  int c0 = lane * 8;
  const int rows = 118;
  int r0 = blockIdx.x * rows;
  int r1 = r0 + rows; if (r1 > N_) r1 = N_;
  float s[8] = {}, q[8] = {};
  for (int r = r0 + rg; r < r1; r += 4){
    u32x4 pv = *reinterpret_cast<const u32x4*>(comb + r * 1024 + 512 + c0);
#pragma unroll
    for (int d = 0; d < 4; d++){
      float v0 = b2f((unsigned short)(pv[d] & 0xffffu));
      float v1 = b2f((unsigned short)(pv[d] >> 16));
      s[2*d]   += v0; q[2*d]   += v0 * v0;
      s[2*d+1] += v1; q[2*d+1] += v1 * v1;
    }
  }
#pragma unroll
  for (int d = 0; d < 8; d++){ lsum[rg][c0 + d] = s[d]; lsq[rg][c0 + d] = q[d]; }
  __syncthreads();
#pragma unroll
  for (int half = 0; half < 2; half++){
    int ch = t + half * 256;
    float a = lsum[0][ch] + lsum[1][ch] + lsum[2][ch] + lsum[3][ch];
    float b = lsq[0][ch] + lsq[1][ch] + lsq[2][ch] + lsq[3][ch];
    psum[blockIdx.x * 512 + ch] = a;
    psq[blockIdx.x * 512 + ch] = b;
  }
}

// ---- finalize BN: 4 blocks x 128 ch ----
__global__ __launch_bounds__(128) void k_bnfin(const float* __restrict__ psum,
                                               const float* __restrict__ psq,
                                               const float* __restrict__ gamma,
                                               const float* __restrict__ beta,
                                               float* __restrict__ scale,
                                               float* __restrict__ shift){
  int ch = blockIdx.x * 128 + threadIdx.x;
  float s0 = 0.f, s1 = 0.f, s2 = 0.f, s3 = 0.f;
  float q0 = 0.f, q1 = 0.f, q2 = 0.f, q3 = 0.f;
  for (int b = 0; b < 256; b += 4){
    s0 += psum[(b    ) * 512 + ch];
    s1 += psum[(b + 1) * 512 + ch];
    s2 += psum[(b + 2) * 512 + ch];
    s3 += psum[(b + 3) * 512 + ch];
    q0 += psq[(b    ) * 512 + ch];
    q1 += psq[(b + 1) * 512 + ch];
    q2 += psq[(b + 2) * 512 + ch];
    q3 += psq[(b + 3) * 512 + ch];
  }
  float sum = (s0 + s1) + (s2 + s3);
  float sq  = (q0 + q1) + (q2 + q3);
  float mu  = sum / (float)N_;
  float var = sq / (float)N_ - mu * mu;
  float inv = rsqrtf(var + 1e-5f);
  float sc  = gamma[ch] * inv;
  scale[ch] = sc;
  shift[ch] = beta[ch] - mu * sc;
}

// ---- GEMM2 (MFMA): out = relu(BN(rst)) @ W_out + b_out, fp32 out ----
__global__ __launch_bounds__(256) void k_gemm2(const unsigned short* __restrict__ comb,
                                               const unsigned short* __restrict__ WtOut,
                                               const float* __restrict__ scale,
                                               const float* __restrict__ shift,
                                               const float* __restrict__ bout,
                                               float* __restrict__ out){
  __shared__ float sc[512], sh[512], bo[128];
  int t = threadIdx.x;
  for (int i = t; i < 512; i += 256){ sc[i] = scale[i]; sh[i] = shift[i]; }
  if (t < 128) bo[t] = bout[t];
  __syncthreads();
  int wave = t >> 6, lane = t & 63, lrow = lane & 15, quad = lane >> 4;
  int rowbase = blockIdx.x * 64 + wave * 16;
  int rr = rowbase + lrow; if (rr > N_ - 1) rr = N_ - 1;
  const unsigned short* arow = comb + rr * 1024 + 512;
  f32x4 acc[8] = {};
#pragma unroll
  for (int kk = 0; kk < 16; kk++){
    int base = kk * 32 + quad * 8;
    Frag a; a.q = *reinterpret_cast<const u32x4*>(arow + base);
#pragma unroll
    for (int i = 0; i < 8; i++){
      float x = b2f(a.us[i]);
      x = fmaf(x, sc[base + i], sh[base + i]);
      a.us[i] = f2b(fmaxf(x, 0.0f));
    }
#pragma unroll
    for (int s = 0; s < 8; s++){
      int col = s * 16 + lrow;
      Frag b; b.q = *reinterpret_cast<const u32x4*>(WtOut + col * 512 + base);
      acc[s] = __builtin_amdgcn_mfma_f32_16x16x32_bf16(a.v, b.v, acc[s], 0, 0, 0);
    }
  }
#pragma unroll
  for (int s = 0; s < 8; s++){
    int col = s * 16 + lrow;
    float bb = bo[col];
#pragma unroll
    for (int j = 0; j < 4; j++){
      int gr = rowbase + quad * 4 + j;
      if (gr < N_) out[gr * 128 + col] = acc[s][j] + bb;
    }
  }
}

extern "C" void kernel_launch(void* const* d_in, const int* in_sizes, int n_in,
                              void* d_out, int out_size, void* d_ws, size_t ws_size,
                              hipStream_t stream){
  const float* feat  = (const float*)d_in[0];
  const int*   src   = (const int*)d_in[1];
  const int*   dst   = (const int*)d_in[2];
  const float* Wfc   = (const float*)d_in[3];
  const float* al    = (const float*)d_in[4];
  const float* ar    = (const float*)d_in[5];
  const float* Wres  = (const float*)d_in[6];
  const float* bias  = (const float*)d_in[7];
  const float* gamma = (const float*)d_in[8];
  const float* beta  = (const float*)d_in[9];
  const float* Wout  = (const float*)d_in[10];
  const float* bout  = (const float*)d_in[11];
  float* out = (float*)d_out;

  char* ws = (char*)d_ws;
  unsigned short* comb   = (unsigned short*)(ws + 0);          // 61,440,000
  unsigned short* Wt     = (unsigned short*)(ws + 61440000);
  unsigned short* WtOut  = (unsigned short*)(ws + 61702144);
  float*          el     = (float*)(ws + 61833216);
  float*          er     = (float*)(ws + 62313216);
  float*          escore = (float*)(ws + 62793216);
  int*            offs   = (int*)(ws + 70473216);
  int*            counts = (int*)(ws + 70593280);
  int*            cursor = (int*)(ws + 70713344);
  int*            eid    = (int*)(ws + 70833408);
  float*          psum   = (float*)(ws + 72753408);
  float*          psq    = (float*)(ws + 73277696);
  float*          scale  = (float*)(ws + 73801984);
  float*          shift  = (float*)(ws + 73804032);
  unsigned short* featb  = (unsigned short*)(ws + 73806080);

  k_initconv<<<640, 256, 0, stream>>>(Wfc, Wres, Wout, feat, Wt, WtOut, featb,
                                      counts, cursor);
  k_hist<<<(E_ + 255) / 256, 256, 0, stream>>>(dst, counts);
  k_scan<<<1, 1024, 0, stream>>>(counts, offs);
  dim3 g1((N_ + 63) / 64, 4);
  k_gemm1<<<g1, 256, 0, stream>>>(featb, Wt, al, ar, comb, el, er);
  k_edge<<<(E_ + 255) / 256, 256, 0, stream>>>(src, dst, el, er, escore, offs, cursor, eid);
  k_soft<<<(N_ + 3) / 4, 256, 0, stream>>>(offs, eid, escore);
  k_aggr<<<((N_ + 3) / 4) * 8, 256, 0, stream>>>(offs, eid, src, escore, comb, bias);
  k_stats<<<256, 256, 0, stream>>>(comb, psum, psq);
  k_bnfin<<<4, 128, 0, stream>>>(psum, psq, gamma, beta, scale, shift);
  k_gemm2<<<(N_ + 63) / 64, 256, 0, stream>>>(comb, WtOut, scale, shift, bout, out);
}

// Round 14
// 390.241 us; speedup vs baseline: 1.4238x; 1.4238x over previous
//
#include <hip/hip_runtime.h>

#define N_  30000
#define E_  480000

typedef short short8 __attribute__((ext_vector_type(8)));
typedef float f32x4  __attribute__((ext_vector_type(4)));
typedef unsigned int u32x4 __attribute__((ext_vector_type(4)));
typedef unsigned int u32x2 __attribute__((ext_vector_type(2)));
union Frag { u32x4 q; short8 v; unsigned short us[8]; };

__device__ __forceinline__ float b2f(unsigned short u){
  union { unsigned int i; float f; } v; v.i = ((unsigned int)u) << 16; return v.f;
}
__device__ __forceinline__ unsigned short f2b(float f){
  union { float f; unsigned int u; } v; v.f = f;
  unsigned int u = v.u;
  return (unsigned short)((u + 0x7fffu + ((u >> 16) & 1u)) >> 16);
}

// ---- init scratch + convert weights AND feat to bf16 ----
__global__ void k_initconv(const float* __restrict__ Wfc, const float* __restrict__ Wres,
                           const float* __restrict__ Wout, const float* __restrict__ feat,
                           unsigned short* __restrict__ Wt, unsigned short* __restrict__ WtOut,
                           unsigned short* __restrict__ featb,
                           int* __restrict__ counts, int* __restrict__ cursor){
  int gid = blockIdx.x * 256 + threadIdx.x;
  int stride = gridDim.x * 256;
  if (gid < N_){ counts[gid] = 0; cursor[gid] = 0; }
  const int total1 = 1024 * 128;
  const int total2 = 128 * 512;
  for (int i = gid; i < total1 + total2; i += stride){
    if (i < total1){
      int c = i >> 7, k = i & 127;
      float v = (c < 512) ? Wfc[k * 512 + c] : Wres[k * 512 + (c - 512)];
      Wt[c * 128 + k] = f2b(v);
    } else {
      int j = i - total1;
      int n = j >> 9, k = j & 511;
      WtOut[n * 512 + k] = f2b(Wout[k * 128 + n]);
    }
  }
  for (int i = gid; i < N_ * 128; i += stride)
    featb[i] = f2b(feat[i]);
}

// ---- histogram of dst ----
__global__ void k_hist(const int* __restrict__ dst, int* __restrict__ counts){
  int e = blockIdx.x * 256 + threadIdx.x;
  if (e < E_) atomicAdd(&counts[dst[e]], 1);
}

// ---- exclusive scan -> offs[0..N_]: 1 block, register-serial + shuffle ----
__global__ __launch_bounds__(1024) void k_scan(const int* __restrict__ counts,
                                               int* __restrict__ offs){
  __shared__ int wsum[16];
  int t = threadIdx.x;
  int lane = t & 63, w = t >> 6;
  int base = t * 32;
  int vals[32];
  int s = 0;
#pragma unroll
  for (int j = 0; j < 32; j++){
    int idx = base + j;
    int v = (idx < N_) ? counts[idx] : 0;
    vals[j] = s;
    s += v;
  }
  int x = s;
  for (int o = 1; o < 64; o <<= 1){
    int y = __shfl_up(x, o);
    if (lane >= o) x += y;
  }
  if (lane == 63) wsum[w] = x;
  __syncthreads();
  if (t < 16){
    int y = wsum[t];
    for (int o = 1; o < 16; o <<= 1){
      int z = __shfl_up(y, o, 16);
      if (t >= o) y += z;
    }
    wsum[t] = y;
  }
  __syncthreads();
  int wbase = (w > 0) ? wsum[w - 1] : 0;
  int ex = wbase + x - s;
#pragma unroll
  for (int j = 0; j < 32; j++){
    int idx = base + j;
    if (idx <= N_) offs[idx] = ex + vals[j];
  }
}

// ---- GEMM1 (MFMA): bf16 feat, 64 rows x 256 cols/block, fused el/er ----
__global__ __launch_bounds__(256) void k_gemm1(const unsigned short* __restrict__ featb,
                                               const unsigned short* __restrict__ Wt,
                                               const float* __restrict__ al,
                                               const float* __restrict__ ar,
                                               unsigned short* __restrict__ comb,
                                               float* __restrict__ el,
                                               float* __restrict__ er){
  int tid = threadIdx.x;
  int wave = tid >> 6, lane = tid & 63;
  int lrow = lane & 15, quad = lane >> 4;
  int rowbase = blockIdx.x * 64 + wave * 16;
  int colbase = blockIdx.y * 256;
  int arow = rowbase + lrow; if (arow > N_ - 1) arow = N_ - 1;
  const unsigned short* aptr = featb + arow * 128 + quad * 8;
  f32x4 acc[16] = {};
#pragma unroll
  for (int kk = 0; kk < 4; kk++){
    Frag a; a.q = *reinterpret_cast<const u32x4*>(aptr + kk * 32);
#pragma unroll
    for (int s = 0; s < 16; s++){
      int col = colbase + s * 16 + lrow;
      Frag b; b.q = *reinterpret_cast<const u32x4*>(Wt + col * 128 + kk * 32 + quad * 8);
      acc[s] = __builtin_amdgcn_mfma_f32_16x16x32_bf16(a.v, b.v, acc[s], 0, 0, 0);
    }
  }
#pragma unroll
  for (int s = 0; s < 16; s++){
    int col = colbase + s * 16 + lrow;
#pragma unroll
    for (int j = 0; j < 4; j++){
      int gr = rowbase + quad * 4 + j;
      if (gr < N_) comb[gr * 1024 + col] = f2b(acc[s][j]);
    }
  }
  if (blockIdx.y < 2){
    int h0 = blockIdx.y * 2;
    float pl[2][4] = {}, pr[2][4] = {};
#pragma unroll
    for (int s = 0; s < 16; s++){
      int hh = s >> 3;
      int d = (s & 7) * 16 + lrow;
      float av = al[(h0 + hh) * 128 + d];
      float rv = ar[(h0 + hh) * 128 + d];
#pragma unroll
      for (int j = 0; j < 4; j++){
        pl[hh][j] += acc[s][j] * av;
        pr[hh][j] += acc[s][j] * rv;
      }
    }
    for (int o = 8; o >= 1; o >>= 1){
#pragma unroll
      for (int hh = 0; hh < 2; hh++)
#pragma unroll
        for (int j = 0; j < 4; j++){
          pl[hh][j] += __shfl_down(pl[hh][j], o, 16);
          pr[hh][j] += __shfl_down(pr[hh][j], o, 16);
        }
    }
    if (lrow == 0){
#pragma unroll
      for (int j = 0; j < 4; j++){
        int gr = rowbase + quad * 4 + j;
        if (gr < N_){
#pragma unroll
          for (int hh = 0; hh < 2; hh++){
            el[gr * 4 + h0 + hh] = pl[hh][j];
            er[gr * 4 + h0 + hh] = pr[hh][j];
          }
        }
      }
    }
  }
}

// ---- per-edge score + scatter INTO CSR ORDER (src_s, es_s) ----
__global__ void k_edge(const int* __restrict__ src, const int* __restrict__ dst,
                       const float* __restrict__ el, const float* __restrict__ er,
                       float* __restrict__ es_s, int* __restrict__ src_s,
                       const int* __restrict__ offs, int* __restrict__ cursor){
  int e = blockIdx.x * 256 + threadIdx.x;
  if (e >= E_) return;
  int s = src[e], d = dst[e];
  f32x4 a = *reinterpret_cast<const f32x4*>(el + s * 4);
  f32x4 b = *reinterpret_cast<const f32x4*>(er + d * 4);
  f32x4 v = a + b;
#pragma unroll
  for (int i = 0; i < 4; i++) v[i] = v[i] > 0.f ? v[i] : 0.2f * v[i];
  int p = atomicAdd(&cursor[d], 1);
  int pos = offs[d] + p;
  *reinterpret_cast<f32x4*>(es_s + pos * 4) = v;
  src_s[pos] = s;
}

// ---- softmax on CSR-contiguous scores, in place -> attention weights ----
// one wave per node; 16-lane group per head; reads are contiguous 256 B/iter.
__global__ __launch_bounds__(256) void k_soft(const int* __restrict__ offs,
                                              float* __restrict__ es_s){
  int wave = threadIdx.x >> 6, lane = threadIdx.x & 63;
  int n = blockIdx.x * 4 + wave;
  if (n >= N_) return;
  int head = lane >> 4, sub = lane & 15;
  int off0 = offs[n], g = offs[n + 1] - off0;
  float m = -1e30f;
  for (int i = sub; i < g; i += 16)
    m = fmaxf(m, es_s[(off0 + i) * 4 + head]);
  for (int o = 8; o >= 1; o >>= 1) m = fmaxf(m, __shfl_xor(m, o, 16));
  float ss = 0.f;
  for (int i = sub; i < g; i += 16)
    ss += __expf(es_s[(off0 + i) * 4 + head] - m);
  for (int o = 8; o >= 1; o >>= 1) ss += __shfl_xor(ss, o, 16);
  float rd = (ss > 0.f) ? 1.0f / ss : 0.f;
  for (int i = sub; i < g; i += 16){
    int idx = (off0 + i) * 4 + head;
    es_s[idx] = __expf(es_s[idx] - m) * rd;
  }
}

// ---- gather: 2 waves/node (256 ch each), 8-way unroll, exp-free, eid-free ----
__global__ __launch_bounds__(256) void k_aggr(const int* __restrict__ offs,
                                              const int* __restrict__ src_s,
                                              const float* __restrict__ w,
                                              unsigned short* __restrict__ comb,
                                              const float* __restrict__ bias){
  int wave = threadIdx.x >> 6, lane = threadIdx.x & 63;
  int n = blockIdx.x * 2 + (wave >> 1);
  if (n >= N_) return;
  int half = wave & 1;
  int c0 = half * 256 + lane * 4;          // 4 channels per lane (8 B loads)
  int head = c0 >> 7;                      // uniform per 32-lane group
  int off0 = offs[n], g = offs[n + 1] - off0;

  float acc[4] = {};
  int i = 0;
  for (; i + 7 < g; i += 8){
    int s8[8];
    float w8[8];
    u32x2 p8[8];
#pragma unroll
    for (int u = 0; u < 8; u++) s8[u] = src_s[off0 + i + u];
#pragma unroll
    for (int u = 0; u < 8; u++) w8[u] = w[(off0 + i + u) * 4 + head];
#pragma unroll
    for (int u = 0; u < 8; u++)
      p8[u] = *reinterpret_cast<const u32x2*>(comb + s8[u] * 1024 + c0);
#pragma unroll
    for (int u = 0; u < 8; u++){
#pragma unroll
      for (int d = 0; d < 2; d++){
        acc[2*d]   += w8[u] * b2f((unsigned short)(p8[u][d] & 0xffffu));
        acc[2*d+1] += w8[u] * b2f((unsigned short)(p8[u][d] >> 16));
      }
    }
  }
  for (; i < g; i++){
    int sv = src_s[off0 + i];
    float a = w[(off0 + i) * 4 + head];
    u32x2 pv = *reinterpret_cast<const u32x2*>(comb + sv * 1024 + c0);
#pragma unroll
    for (int d = 0; d < 2; d++){
      acc[2*d]   += a * b2f((unsigned short)(pv[d] & 0xffffu));
      acc[2*d+1] += a * b2f((unsigned short)(pv[d] >> 16));
    }
  }

  // residual + bias, write rst (4 ch = 8 B)
  unsigned short* rp = comb + n * 1024 + 512 + c0;
  u32x2 rv = *reinterpret_cast<const u32x2*>(rp);
  f32x4 bb = *reinterpret_cast<const f32x4*>(bias + c0);
  u32x2 ov;
#pragma unroll
  for (int d = 0; d < 2; d++){
    float v0 = acc[2*d]   + b2f((unsigned short)(rv[d] & 0xffffu)) + bb[2*d];
    float v1 = acc[2*d+1] + b2f((unsigned short)(rv[d] >> 16))     + bb[2*d+1];
    ov[d] = (unsigned int)f2b(v0) | ((unsigned int)f2b(v1) << 16);
  }
  *reinterpret_cast<u32x2*>(rp) = ov;
}

// ---- BN stats: 256 blocks, wave-register partials + LDS block-reduce ----
__global__ __launch_bounds__(256) void k_stats(const unsigned short* __restrict__ comb,
                                               float* __restrict__ psum,
                                               float* __restrict__ psq){
  __shared__ float lsum[4][512];
  __shared__ float lsq[4][512];
  int t = threadIdx.x, lane = t & 63, rg = t >> 6;
  int c0 = lane * 8;
  const int rows = 118;
  int r0 = blockIdx.x * rows;
  int r1 = r0 + rows; if (r1 > N_) r1 = N_;
  float s[8] = {}, q[8] = {};
  for (int r = r0 + rg; r < r1; r += 4){
    u32x4 pv = *reinterpret_cast<const u32x4*>(comb + r * 1024 + 512 + c0);
#pragma unroll
    for (int d = 0; d < 4; d++){
      float v0 = b2f((unsigned short)(pv[d] & 0xffffu));
      float v1 = b2f((unsigned short)(pv[d] >> 16));
      s[2*d]   += v0; q[2*d]   += v0 * v0;
      s[2*d+1] += v1; q[2*d+1] += v1 * v1;
    }
  }
#pragma unroll
  for (int d = 0; d < 8; d++){ lsum[rg][c0 + d] = s[d]; lsq[rg][c0 + d] = q[d]; }
  __syncthreads();
#pragma unroll
  for (int half = 0; half < 2; half++){
    int ch = t + half * 256;
    float a = lsum[0][ch] + lsum[1][ch] + lsum[2][ch] + lsum[3][ch];
    float b = lsq[0][ch] + lsq[1][ch] + lsq[2][ch] + lsq[3][ch];
    psum[blockIdx.x * 512 + ch] = a;
    psq[blockIdx.x * 512 + ch] = b;
  }
}

// ---- finalize BN: 4 blocks x 128 ch ----
__global__ __launch_bounds__(128) void k_bnfin(const float* __restrict__ psum,
                                               const float* __restrict__ psq,
                                               const float* __restrict__ gamma,
                                               const float* __restrict__ beta,
                                               float* __restrict__ scale,
                                               float* __restrict__ shift){
  int ch = blockIdx.x * 128 + threadIdx.x;
  float s0 = 0.f, s1 = 0.f, s2 = 0.f, s3 = 0.f;
  float q0 = 0.f, q1 = 0.f, q2 = 0.f, q3 = 0.f;
  for (int b = 0; b < 256; b += 4){
    s0 += psum[(b    ) * 512 + ch];
    s1 += psum[(b + 1) * 512 + ch];
    s2 += psum[(b + 2) * 512 + ch];
    s3 += psum[(b + 3) * 512 + ch];
    q0 += psq[(b    ) * 512 + ch];
    q1 += psq[(b + 1) * 512 + ch];
    q2 += psq[(b + 2) * 512 + ch];
    q3 += psq[(b + 3) * 512 + ch];
  }
  float sum = (s0 + s1) + (s2 + s3);
  float sq  = (q0 + q1) + (q2 + q3);
  float mu  = sum / (float)N_;
  float var = sq / (float)N_ - mu * mu;
  float inv = rsqrtf(var + 1e-5f);
  float sc  = gamma[ch] * inv;
  scale[ch] = sc;
  shift[ch] = beta[ch] - mu * sc;
}

// ---- GEMM2 (MFMA): out = relu(BN(rst)) @ W_out + b_out, fp32 out ----
__global__ __launch_bounds__(256) void k_gemm2(const unsigned short* __restrict__ comb,
                                               const unsigned short* __restrict__ WtOut,
                                               const float* __restrict__ scale,
                                               const float* __restrict__ shift,
                                               const float* __restrict__ bout,
                                               float* __restrict__ out){
  __shared__ float sc[512], sh[512], bo[128];
  int t = threadIdx.x;
  for (int i = t; i < 512; i += 256){ sc[i] = scale[i]; sh[i] = shift[i]; }
  if (t < 128) bo[t] = bout[t];
  __syncthreads();
  int wave = t >> 6, lane = t & 63, lrow = lane & 15, quad = lane >> 4;
  int rowbase = blockIdx.x * 64 + wave * 16;
  int rr = rowbase + lrow; if (rr > N_ - 1) rr = N_ - 1;
  const unsigned short* arow = comb + rr * 1024 + 512;
  f32x4 acc[8] = {};
#pragma unroll
  for (int kk = 0; kk < 16; kk++){
    int base = kk * 32 + quad * 8;
    Frag a; a.q = *reinterpret_cast<const u32x4*>(arow + base);
#pragma unroll
    for (int i = 0; i < 8; i++){
      float x = b2f(a.us[i]);
      x = fmaf(x, sc[base + i], sh[base + i]);
      a.us[i] = f2b(fmaxf(x, 0.0f));
    }
#pragma unroll
    for (int s = 0; s < 8; s++){
      int col = s * 16 + lrow;
      Frag b; b.q = *reinterpret_cast<const u32x4*>(WtOut + col * 512 + base);
      acc[s] = __builtin_amdgcn_mfma_f32_16x16x32_bf16(a.v, b.v, acc[s], 0, 0, 0);
    }
  }
#pragma unroll
  for (int s = 0; s < 8; s++){
    int col = s * 16 + lrow;
    float bb = bo[col];
#pragma unroll
    for (int j = 0; j < 4; j++){
      int gr = rowbase + quad * 4 + j;
      if (gr < N_) out[gr * 128 + col] = acc[s][j] + bb;
    }
  }
}

extern "C" void kernel_launch(void* const* d_in, const int* in_sizes, int n_in,
                              void* d_out, int out_size, void* d_ws, size_t ws_size,
                              hipStream_t stream){
  const float* feat  = (const float*)d_in[0];
  const int*   src   = (const int*)d_in[1];
  const int*   dst   = (const int*)d_in[2];
  const float* Wfc   = (const float*)d_in[3];
  const float* al    = (const float*)d_in[4];
  const float* ar    = (const float*)d_in[5];
  const float* Wres  = (const float*)d_in[6];
  const float* bias  = (const float*)d_in[7];
  const float* gamma = (const float*)d_in[8];
  const float* beta  = (const float*)d_in[9];
  const float* Wout  = (const float*)d_in[10];
  const float* bout  = (const float*)d_in[11];
  float* out = (float*)d_out;

  char* ws = (char*)d_ws;
  unsigned short* comb   = (unsigned short*)(ws + 0);          // 61,440,000
  unsigned short* Wt     = (unsigned short*)(ws + 61440000);
  unsigned short* WtOut  = (unsigned short*)(ws + 61702144);
  float*          el     = (float*)(ws + 61833216);
  float*          er     = (float*)(ws + 62313216);
  float*          es_s   = (float*)(ws + 62793216);            // CSR-ordered scores/weights
  int*            offs   = (int*)(ws + 70473216);
  int*            counts = (int*)(ws + 70593280);
  int*            cursor = (int*)(ws + 70713344);
  int*            src_s  = (int*)(ws + 70833408);              // CSR-ordered src
  float*          psum   = (float*)(ws + 72753408);
  float*          psq    = (float*)(ws + 73277696);
  float*          scale  = (float*)(ws + 73801984);
  float*          shift  = (float*)(ws + 73804032);
  unsigned short* featb  = (unsigned short*)(ws + 73806080);

  k_initconv<<<640, 256, 0, stream>>>(Wfc, Wres, Wout, feat, Wt, WtOut, featb,
                                      counts, cursor);
  k_hist<<<(E_ + 255) / 256, 256, 0, stream>>>(dst, counts);
  k_scan<<<1, 1024, 0, stream>>>(counts, offs);
  dim3 g1((N_ + 63) / 64, 4);
  k_gemm1<<<g1, 256, 0, stream>>>(featb, Wt, al, ar, comb, el, er);
  k_edge<<<(E_ + 255) / 256, 256, 0, stream>>>(src, dst, el, er, es_s, src_s, offs, cursor);
  k_soft<<<(N_ + 3) / 4, 256, 0, stream>>>(offs, es_s);
  k_aggr<<<(N_ + 1) / 2, 256, 0, stream>>>(offs, src_s, es_s, comb, bias);
  k_stats<<<256, 256, 0, stream>>>(comb, psum, psq);
  k_bnfin<<<4, 128, 0, stream>>>(psum, psq, gamma, beta, scale, shift);
  k_gemm2<<<(N_ + 63) / 64, 256, 0, stream>>>(comb, WtOut, scale, shift, bout, out);
}

// Round 15
// 329.144 us; speedup vs baseline: 1.6881x; 1.1856x over previous
//
#include <hip/hip_runtime.h>

#define N_  30000
#define E_  480000

typedef short short8 __attribute__((ext_vector_type(8)));
typedef float f32x4  __attribute__((ext_vector_type(4)));
typedef unsigned int u32x4 __attribute__((ext_vector_type(4)));
typedef unsigned int u32x2 __attribute__((ext_vector_type(2)));
union Frag { u32x4 q; short8 v; unsigned short us[8]; };

__device__ __forceinline__ float b2f(unsigned short u){
  union { unsigned int i; float f; } v; v.i = ((unsigned int)u) << 16; return v.f;
}
__device__ __forceinline__ unsigned short f2b(float f){
  union { float f; unsigned int u; } v; v.f = f;
  unsigned int u = v.u;
  return (unsigned short)((u + 0x7fffu + ((u >> 16) & 1u)) >> 16);
}

// ---- init scratch + convert weights AND feat to bf16 ----
__global__ void k_initconv(const float* __restrict__ Wfc, const float* __restrict__ Wres,
                           const float* __restrict__ Wout, const float* __restrict__ feat,
                           unsigned short* __restrict__ Wt, unsigned short* __restrict__ WtOut,
                           unsigned short* __restrict__ featb,
                           int* __restrict__ counts, int* __restrict__ cursor){
  int gid = blockIdx.x * 256 + threadIdx.x;
  int stride = gridDim.x * 256;
  if (gid < N_){ counts[gid] = 0; cursor[gid] = 0; }
  const int total1 = 1024 * 128;
  const int total2 = 128 * 512;
  for (int i = gid; i < total1 + total2; i += stride){
    if (i < total1){
      int c = i >> 7, k = i & 127;
      float v = (c < 512) ? Wfc[k * 512 + c] : Wres[k * 512 + (c - 512)];
      Wt[c * 128 + k] = f2b(v);
    } else {
      int j = i - total1;
      int n = j >> 9, k = j & 511;
      WtOut[n * 512 + k] = f2b(Wout[k * 128 + n]);
    }
  }
  for (int i = gid; i < N_ * 128; i += stride)
    featb[i] = f2b(feat[i]);
}

// ---- histogram of dst ----
__global__ void k_hist(const int* __restrict__ dst, int* __restrict__ counts){
  int e = blockIdx.x * 256 + threadIdx.x;
  if (e < E_) atomicAdd(&counts[dst[e]], 1);
}

// ---- exclusive scan -> offs[0..N_]: 1 block, register-serial + shuffle ----
__global__ __launch_bounds__(1024) void k_scan(const int* __restrict__ counts,
                                               int* __restrict__ offs){
  __shared__ int wsum[16];
  int t = threadIdx.x;
  int lane = t & 63, w = t >> 6;
  int base = t * 32;
  int vals[32];
  int s = 0;
#pragma unroll
  for (int j = 0; j < 32; j++){
    int idx = base + j;
    int v = (idx < N_) ? counts[idx] : 0;
    vals[j] = s;
    s += v;
  }
  int x = s;
  for (int o = 1; o < 64; o <<= 1){
    int y = __shfl_up(x, o);
    if (lane >= o) x += y;
  }
  if (lane == 63) wsum[w] = x;
  __syncthreads();
  if (t < 16){
    int y = wsum[t];
    for (int o = 1; o < 16; o <<= 1){
      int z = __shfl_up(y, o, 16);
      if (t >= o) y += z;
    }
    wsum[t] = y;
  }
  __syncthreads();
  int wbase = (w > 0) ? wsum[w - 1] : 0;
  int ex = wbase + x - s;
#pragma unroll
  for (int j = 0; j < 32; j++){
    int idx = base + j;
    if (idx <= N_) offs[idx] = ex + vals[j];
  }
}

// ---- GEMM1 (MFMA, swapped operands + LDS-staged weights) ----
// grid (469, 4): 64 rows x 256 cols/block. Per kk: stage Wt slice [256c][32k].
// D layout after swap: lane&15 = feat row, quad*4+j = channel -> 8B stores.
__global__ __launch_bounds__(256) void k_gemm1(const unsigned short* __restrict__ featb,
                                               const unsigned short* __restrict__ Wt,
                                               const float* __restrict__ al,
                                               const float* __restrict__ ar,
                                               unsigned short* __restrict__ comb,
                                               float* __restrict__ el,
                                               float* __restrict__ er){
  __shared__ unsigned short wsl[256 * 40];   // stride 40 shorts: 2-way bank alias only
  int tid = threadIdx.x;
  int wave = tid >> 6, lane = tid & 63;
  int lrow = lane & 15, quad = lane >> 4;
  int rowbase = blockIdx.x * 64 + wave * 16;
  int colbase = blockIdx.y * 256;
  int arow = rowbase + lrow; if (arow > N_ - 1) arow = N_ - 1;
  const unsigned short* aptr = featb + arow * 128 + quad * 8;
  f32x4 acc[16] = {};
  for (int kk = 0; kk < 4; kk++){
    __syncthreads();
#pragma unroll
    for (int i = 0; i < 4; i++){
      int c = tid + i * 256;                 // 16B chunk id 0..1023
      int col = c >> 2, w = (c & 3) * 8;
      u32x4 v = *reinterpret_cast<const u32x4*>(Wt + (colbase + col) * 128 + kk * 32 + w);
      *reinterpret_cast<u32x4*>(&wsl[col * 40 + w]) = v;
    }
    __syncthreads();
    Frag a; a.q = *reinterpret_cast<const u32x4*>(aptr + kk * 32);
#pragma unroll
    for (int s = 0; s < 16; s++){
      Frag b; b.q = *reinterpret_cast<const u32x4*>(&wsl[(s * 16 + lrow) * 40 + quad * 8]);
      acc[s] = __builtin_amdgcn_mfma_f32_16x16x32_bf16(b.v, a.v, acc[s], 0, 0, 0);
    }
  }
  int gr = rowbase + lrow;
  if (gr < N_){
    unsigned short* crow = comb + gr * 1024 + colbase;
#pragma unroll
    for (int s = 0; s < 16; s++){
      u32x2 ov;
#pragma unroll
      for (int d = 0; d < 2; d++)
        ov[d] = (unsigned int)f2b(acc[s][2*d]) | ((unsigned int)f2b(acc[s][2*d+1]) << 16);
      *reinterpret_cast<u32x2*>(crow + s * 16 + quad * 4) = ov;
    }
  }
  if (blockIdx.y < 2){
    int h0 = blockIdx.y * 2;
    float pl[2] = {}, pr[2] = {};
#pragma unroll
    for (int s = 0; s < 16; s++){
      int hh = s >> 3;
      int dbase = (s & 7) * 16 + quad * 4;
      f32x4 av = *reinterpret_cast<const f32x4*>(al + (h0 + hh) * 128 + dbase);
      f32x4 rv = *reinterpret_cast<const f32x4*>(ar + (h0 + hh) * 128 + dbase);
#pragma unroll
      for (int j = 0; j < 4; j++){
        pl[hh] += acc[s][j] * av[j];
        pr[hh] += acc[s][j] * rv[j];
      }
    }
#pragma unroll
    for (int hh = 0; hh < 2; hh++){
      pl[hh] += __shfl_xor(pl[hh], 16);
      pl[hh] += __shfl_xor(pl[hh], 32);
      pr[hh] += __shfl_xor(pr[hh], 16);
      pr[hh] += __shfl_xor(pr[hh], 32);
    }
    if (quad == 0 && gr < N_){
#pragma unroll
      for (int hh = 0; hh < 2; hh++){
        el[gr * 4 + h0 + hh] = pl[hh];
        er[gr * 4 + h0 + hh] = pr[hh];
      }
    }
  }
}

// ---- per-edge score + scatter INTO CSR ORDER (src_s, es_s) ----
__global__ void k_edge(const int* __restrict__ src, const int* __restrict__ dst,
                       const float* __restrict__ el, const float* __restrict__ er,
                       float* __restrict__ es_s, int* __restrict__ src_s,
                       const int* __restrict__ offs, int* __restrict__ cursor){
  int e = blockIdx.x * 256 + threadIdx.x;
  if (e >= E_) return;
  int s = src[e], d = dst[e];
  f32x4 a = *reinterpret_cast<const f32x4*>(el + s * 4);
  f32x4 b = *reinterpret_cast<const f32x4*>(er + d * 4);
  f32x4 v = a + b;
#pragma unroll
  for (int i = 0; i < 4; i++) v[i] = v[i] > 0.f ? v[i] : 0.2f * v[i];
  int p = atomicAdd(&cursor[d], 1);
  int pos = offs[d] + p;
  *reinterpret_cast<f32x4*>(es_s + pos * 4) = v;
  src_s[pos] = s;
}

// ---- softmax on CSR-contiguous scores, in place -> attention weights ----
__global__ __launch_bounds__(256) void k_soft(const int* __restrict__ offs,
                                              float* __restrict__ es_s){
  int wave = threadIdx.x >> 6, lane = threadIdx.x & 63;
  int n = blockIdx.x * 4 + wave;
  if (n >= N_) return;
  int head = lane >> 4, sub = lane & 15;
  int off0 = offs[n], g = offs[n + 1] - off0;
  float m = -1e30f;
  for (int i = sub; i < g; i += 16)
    m = fmaxf(m, es_s[(off0 + i) * 4 + head]);
  for (int o = 8; o >= 1; o >>= 1) m = fmaxf(m, __shfl_xor(m, o, 16));
  float ss = 0.f;
  for (int i = sub; i < g; i += 16)
    ss += __expf(es_s[(off0 + i) * 4 + head] - m);
  for (int o = 8; o >= 1; o >>= 1) ss += __shfl_xor(ss, o, 16);
  float rd = (ss > 0.f) ? 1.0f / ss : 0.f;
  for (int i = sub; i < g; i += 16){
    int idx = (off0 + i) * 4 + head;
    es_s[idx] = __expf(es_s[idx] - m) * rd;
  }
}

// ---- gather: 2 waves/node (256 ch each), 8-way unroll, exp-free, eid-free ----
__global__ __launch_bounds__(256) void k_aggr(const int* __restrict__ offs,
                                              const int* __restrict__ src_s,
                                              const float* __restrict__ w,
                                              unsigned short* __restrict__ comb,
                                              const float* __restrict__ bias){
  int wave = threadIdx.x >> 6, lane = threadIdx.x & 63;
  int n = blockIdx.x * 2 + (wave >> 1);
  if (n >= N_) return;
  int half = wave & 1;
  int c0 = half * 256 + lane * 4;
  int head = c0 >> 7;
  int off0 = offs[n], g = offs[n + 1] - off0;

  float acc[4] = {};
  int i = 0;
  for (; i + 7 < g; i += 8){
    int s8[8];
    float w8[8];
    u32x2 p8[8];
#pragma unroll
    for (int u = 0; u < 8; u++) s8[u] = src_s[off0 + i + u];
#pragma unroll
    for (int u = 0; u < 8; u++) w8[u] = w[(off0 + i + u) * 4 + head];
#pragma unroll
    for (int u = 0; u < 8; u++)
      p8[u] = *reinterpret_cast<const u32x2*>(comb + s8[u] * 1024 + c0);
#pragma unroll
    for (int u = 0; u < 8; u++){
#pragma unroll
      for (int d = 0; d < 2; d++){
        acc[2*d]   += w8[u] * b2f((unsigned short)(p8[u][d] & 0xffffu));
        acc[2*d+1] += w8[u] * b2f((unsigned short)(p8[u][d] >> 16));
      }
    }
  }
  for (; i < g; i++){
    int sv = src_s[off0 + i];
    float a = w[(off0 + i) * 4 + head];
    u32x2 pv = *reinterpret_cast<const u32x2*>(comb + sv * 1024 + c0);
#pragma unroll
    for (int d = 0; d < 2; d++){
      acc[2*d]   += a * b2f((unsigned short)(pv[d] & 0xffffu));
      acc[2*d+1] += a * b2f((unsigned short)(pv[d] >> 16));
    }
  }

  unsigned short* rp = comb + n * 1024 + 512 + c0;
  u32x2 rv = *reinterpret_cast<const u32x2*>(rp);
  f32x4 bb = *reinterpret_cast<const f32x4*>(bias + c0);
  u32x2 ov;
#pragma unroll
  for (int d = 0; d < 2; d++){
    float v0 = acc[2*d]   + b2f((unsigned short)(rv[d] & 0xffffu)) + bb[2*d];
    float v1 = acc[2*d+1] + b2f((unsigned short)(rv[d] >> 16))     + bb[2*d+1];
    ov[d] = (unsigned int)f2b(v0) | ((unsigned int)f2b(v1) << 16);
  }
  *reinterpret_cast<u32x2*>(rp) = ov;
}

// ---- BN stats: 256 blocks, wave-register partials + LDS block-reduce ----
__global__ __launch_bounds__(256) void k_stats(const unsigned short* __restrict__ comb,
                                               float* __restrict__ psum,
                                               float* __restrict__ psq){
  __shared__ float lsum[4][512];
  __shared__ float lsq[4][512];
  int t = threadIdx.x, lane = t & 63, rg = t >> 6;
  int c0 = lane * 8;
  const int rows = 118;
  int r0 = blockIdx.x * rows;
  int r1 = r0 + rows; if (r1 > N_) r1 = N_;
  float s[8] = {}, q[8] = {};
  for (int r = r0 + rg; r < r1; r += 4){
    u32x4 pv = *reinterpret_cast<const u32x4*>(comb + r * 1024 + 512 + c0);
#pragma unroll
    for (int d = 0; d < 4; d++){
      float v0 = b2f((unsigned short)(pv[d] & 0xffffu));
      float v1 = b2f((unsigned short)(pv[d] >> 16));
      s[2*d]   += v0; q[2*d]   += v0 * v0;
      s[2*d+1] += v1; q[2*d+1] += v1 * v1;
    }
  }
#pragma unroll
  for (int d = 0; d < 8; d++){ lsum[rg][c0 + d] = s[d]; lsq[rg][c0 + d] = q[d]; }
  __syncthreads();
#pragma unroll
  for (int half = 0; half < 2; half++){
    int ch = t + half * 256;
    float a = lsum[0][ch] + lsum[1][ch] + lsum[2][ch] + lsum[3][ch];
    float b = lsq[0][ch] + lsq[1][ch] + lsq[2][ch] + lsq[3][ch];
    psum[blockIdx.x * 512 + ch] = a;
    psq[blockIdx.x * 512 + ch] = b;
  }
}

// ---- finalize BN: 4 blocks x 128 ch ----
__global__ __launch_bounds__(128) void k_bnfin(const float* __restrict__ psum,
                                               const float* __restrict__ psq,
                                               const float* __restrict__ gamma,
                                               const float* __restrict__ beta,
                                               float* __restrict__ scale,
                                               float* __restrict__ shift){
  int ch = blockIdx.x * 128 + threadIdx.x;
  float s0 = 0.f, s1 = 0.f, s2 = 0.f, s3 = 0.f;
  float q0 = 0.f, q1 = 0.f, q2 = 0.f, q3 = 0.f;
  for (int b = 0; b < 256; b += 4){
    s0 += psum[(b    ) * 512 + ch];
    s1 += psum[(b + 1) * 512 + ch];
    s2 += psum[(b + 2) * 512 + ch];
    s3 += psum[(b + 3) * 512 + ch];
    q0 += psq[(b    ) * 512 + ch];
    q1 += psq[(b + 1) * 512 + ch];
    q2 += psq[(b + 2) * 512 + ch];
    q3 += psq[(b + 3) * 512 + ch];
  }
  float sum = (s0 + s1) + (s2 + s3);
  float sq  = (q0 + q1) + (q2 + q3);
  float mu  = sum / (float)N_;
  float var = sq / (float)N_ - mu * mu;
  float inv = rsqrtf(var + 1e-5f);
  float sc  = gamma[ch] * inv;
  scale[ch] = sc;
  shift[ch] = beta[ch] - mu * sc;
}

// ---- GEMM2 (MFMA, swapped operands + per-kk LDS-staged weights), fp32 out ----
__global__ __launch_bounds__(256) void k_gemm2(const unsigned short* __restrict__ comb,
                                               const unsigned short* __restrict__ WtOut,
                                               const float* __restrict__ scale,
                                               const float* __restrict__ shift,
                                               const float* __restrict__ bout,
                                               float* __restrict__ out){
  __shared__ float sc[512], sh[512];
  __shared__ unsigned short wsl[128 * 40];
  int t = threadIdx.x;
  for (int i = t; i < 512; i += 256){ sc[i] = scale[i]; sh[i] = shift[i]; }
  int wave = t >> 6, lane = t & 63, lrow = lane & 15, quad = lane >> 4;
  int rowbase = blockIdx.x * 64 + wave * 16;
  int rr = rowbase + lrow; if (rr > N_ - 1) rr = N_ - 1;
  const unsigned short* arow = comb + rr * 1024 + 512;
  f32x4 acc[8] = {};
  for (int kk = 0; kk < 16; kk++){
    __syncthreads();
#pragma unroll
    for (int i = 0; i < 2; i++){
      int c = t + i * 256;                   // 16B chunk id 0..511
      int col = c >> 2, w = (c & 3) * 8;
      u32x4 v = *reinterpret_cast<const u32x4*>(WtOut + col * 512 + kk * 32 + w);
      *reinterpret_cast<u32x4*>(&wsl[col * 40 + w]) = v;
    }
    __syncthreads();
    int base = kk * 32 + quad * 8;
    Frag a; a.q = *reinterpret_cast<const u32x4*>(arow + base);
#pragma unroll
    for (int i2 = 0; i2 < 8; i2++){
      float x = b2f(a.us[i2]);
      x = fmaf(x, sc[base + i2], sh[base + i2]);
      a.us[i2] = f2b(fmaxf(x, 0.0f));
    }
#pragma unroll
    for (int s = 0; s < 8; s++){
      Frag b; b.q = *reinterpret_cast<const u32x4*>(&wsl[(s * 16 + lrow) * 40 + quad * 8]);
      acc[s] = __builtin_amdgcn_mfma_f32_16x16x32_bf16(b.v, a.v, acc[s], 0, 0, 0);
    }
  }
  int gr = rowbase + lrow;
  if (gr < N_){
    float* orow = out + gr * 128;
#pragma unroll
    for (int s = 0; s < 8; s++){
      int cb = s * 16 + quad * 4;
      f32x4 bb = *reinterpret_cast<const f32x4*>(bout + cb);
      f32x4 ov;
#pragma unroll
      for (int j = 0; j < 4; j++) ov[j] = acc[s][j] + bb[j];
      *reinterpret_cast<f32x4*>(orow + cb) = ov;
    }
  }
}

extern "C" void kernel_launch(void* const* d_in, const int* in_sizes, int n_in,
                              void* d_out, int out_size, void* d_ws, size_t ws_size,
                              hipStream_t stream){
  const float* feat  = (const float*)d_in[0];
  const int*   src   = (const int*)d_in[1];
  const int*   dst   = (const int*)d_in[2];
  const float* Wfc   = (const float*)d_in[3];
  const float* al    = (const float*)d_in[4];
  const float* ar    = (const float*)d_in[5];
  const float* Wres  = (const float*)d_in[6];
  const float* bias  = (const float*)d_in[7];
  const float* gamma = (const float*)d_in[8];
  const float* beta  = (const float*)d_in[9];
  const float* Wout  = (const float*)d_in[10];
  const float* bout  = (const float*)d_in[11];
  float* out = (float*)d_out;

  char* ws = (char*)d_ws;
  unsigned short* comb   = (unsigned short*)(ws + 0);          // 61,440,000
  unsigned short* Wt     = (unsigned short*)(ws + 61440000);
  unsigned short* WtOut  = (unsigned short*)(ws + 61702144);
  float*          el     = (float*)(ws + 61833216);
  float*          er     = (float*)(ws + 62313216);
  float*          es_s   = (float*)(ws + 62793216);
  int*            offs   = (int*)(ws + 70473216);
  int*            counts = (int*)(ws + 70593280);
  int*            cursor = (int*)(ws + 70713344);
  int*            src_s  = (int*)(ws + 70833408);
  float*          psum   = (float*)(ws + 72753408);
  float*          psq    = (float*)(ws + 73277696);
  float*          scale  = (float*)(ws + 73801984);
  float*          shift  = (float*)(ws + 73804032);
  unsigned short* featb  = (unsigned short*)(ws + 73806080);

  k_initconv<<<640, 256, 0, stream>>>(Wfc, Wres, Wout, feat, Wt, WtOut, featb,
                                      counts, cursor);
  k_hist<<<(E_ + 255) / 256, 256, 0, stream>>>(dst, counts);
  k_scan<<<1, 1024, 0, stream>>>(counts, offs);
  dim3 g1((N_ + 63) / 64, 4);
  k_gemm1<<<g1, 256, 0, stream>>>(featb, Wt, al, ar, comb, el, er);
  k_edge<<<(E_ + 255) / 256, 256, 0, stream>>>(src, dst, el, er, es_s, src_s, offs, cursor);
  k_soft<<<(N_ + 3) / 4, 256, 0, stream>>>(offs, es_s);
  k_aggr<<<(N_ + 1) / 2, 256, 0, stream>>>(offs, src_s, es_s, comb, bias);
  k_stats<<<256, 256, 0, stream>>>(comb, psum, psq);
  k_bnfin<<<4, 128, 0, stream>>>(psum, psq, gamma, beta, scale, shift);
  k_gemm2<<<(N_ + 63) / 64, 256, 0, stream>>>(comb, WtOut, scale, shift, bout, out);
}